// Round 13
// baseline (44.194 us; speedup 1.0000x reference)
//
#include <hip/hip_runtime.h>

using short8 = __attribute__((ext_vector_type(8))) short;
using h8     = __attribute__((ext_vector_type(8))) _Float16;
using h2     = __attribute__((ext_vector_type(2))) _Float16;
using f32x4  = __attribute__((ext_vector_type(4))) float;

#define NB  8
#define NTH 512
// ws layout (ushort units, all f16 bits)
#define WBIN_OFF 0         // [64 n][192 k]
#define WFIN_OFF 12288     // [160 n][64 k]
#define EMBO_OFF 22528     // [100 r][64 k] linear
#define LTAB_OFF 28928     // [6 p][100 v][64 n]
#define WS_USHORTS 67328

__device__ __forceinline__ unsigned short f2h_bits(float v) {
    _Float16 h = (_Float16)v;
    return *reinterpret_cast<unsigned short*>(&h);
}
__device__ __forceinline__ h8 ld8h(const unsigned short* p) {
    return *reinterpret_cast<const h8*>(p);
}
__device__ __forceinline__ short8 ld8s(const unsigned short* p) {
    return *reinterpret_cast<const short8*>(p);
}
__device__ __forceinline__ f32x4 mf(h8 a, h8 b, f32x4 c) {
    return __builtin_amdgcn_mfma_f32_16x16x32_f16(a, b, c, 0, 0, 0);
}

// ---------------- prep: build f16 weights + leaf lookup tables --------------
__global__ void prep_kernel(const float* __restrict__ emb_pred,
                            const float* __restrict__ emb_var,
                            const float* __restrict__ emb_op,
                            const float* __restrict__ W_pred,
                            const float* __restrict__ W_bin,
                            const float* __restrict__ W_final,
                            unsigned short* __restrict__ ws) {
    for (int i = blockIdx.x * blockDim.x + threadIdx.x; i < WS_USHORTS;
         i += gridDim.x * blockDim.x) {
        float v = 0.f;
        if (i < WFIN_OFF) {                      // W_bin [64][192]
            int n = i / 192, k = i - n * 192, p = k >> 6, j = k & 63;
            if (n < 50 && j < 50) v = W_bin[n * 150 + p * 50 + j];
        } else if (i < EMBO_OFF) {               // W_final [160][64]
            int t = i - WFIN_OFF, o = t >> 6, k = t & 63;
            if (o < 155 && k < 50) v = W_final[o * 50 + k];
        } else if (i < LTAB_OFF) {               // emb_op [100][64]
            int t = i - EMBO_OFF, r = t >> 6, j = t & 63;
            if (j < 50) v = emb_op[r * 50 + j];
        } else {                                 // leaf tables [6][100][64]
            int t = i - LTAB_OFF;
            int p = t / 6400, rest = t - p * 6400, vv = rest >> 6, n = rest & 63;
            if (n < 50) {
                const float* e = (p == 0) ? (emb_pred + vv * 50) : (emb_var + vv * 50);
                const float* wr = W_pred + n * 300 + p * 50;
                float acc = 0.f;
                for (int k = 0; k < 50; ++k) acc += e[k] * wr[k];
                v = acc;
            }
        }
        ws[i] = f2h_bits(v);
    }
}

// Paired tree node: MFMA M-rows 0-7 = (node A, batch 0-7), rows 8-15 = node B.
// A-rows selected per-lane (l15<8 -> A), D-rows per-quad (quad<2 -> A).
// Op embedding fragments gathered from GLOBAL ws (L1-resident, 12.8 KB).
#define TNODEP(NT0, NTN, CLA, CRA, GNA, CLB, CRB, GNB, DSTA, DSTB) do {         \
    const unsigned short* rl_ = (l15 < 8) ? s_x[CLA] : s_x[CLB];                \
    const unsigned short* rr_ = (l15 < 8) ? s_x[CRA] : s_x[CRB];                \
    int gn_ = (l15 < 8) ? (GNA) : (GNB);                                        \
    int r_  = s_op[gn_ * 8 + (l15 & 7)];                                        \
    int mr_ = l15 & 7;                                                          \
    h8 aL0 = ld8h(rl_ + mr_ * 64 + ((quad ^ mr_) << 3));                        \
    h8 aL1 = ld8h(rl_ + mr_ * 64 + (((quad + 4) ^ mr_) << 3));                  \
    h8 aO0 = ld8h(ws + EMBO_OFF + r_ * 64 + quad * 8);                          \
    h8 aO1 = ld8h(ws + EMBO_OFF + r_ * 64 + (quad + 4) * 8);                    \
    h8 aR0 = ld8h(rr_ + mr_ * 64 + ((quad ^ mr_) << 3));                        \
    h8 aR1 = ld8h(rr_ + mr_ * 64 + (((quad + 4) ^ mr_) << 3));                  \
    f32x4 acc_[NTN];                                                            \
    _Pragma("unroll") for (int i_ = 0; i_ < (NTN); ++i_) {                      \
        acc_[i_] = (f32x4){0.f, 0.f, 0.f, 0.f};                                 \
        acc_[i_] = mf(aL0, wb[0][0][(NT0) + i_], acc_[i_]);                     \
        acc_[i_] = mf(aL1, wb[0][1][(NT0) + i_], acc_[i_]);                     \
        acc_[i_] = mf(aO0, wb[1][0][(NT0) + i_], acc_[i_]);                     \
        acc_[i_] = mf(aO1, wb[1][1][(NT0) + i_], acc_[i_]);                     \
        acc_[i_] = mf(aR0, wb[2][0][(NT0) + i_], acc_[i_]);                     \
        acc_[i_] = mf(aR1, wb[2][1][(NT0) + i_], acc_[i_]);                     \
    }                                                                           \
    unsigned short* drow_ = (quad < 2) ? s_x[DSTA] : s_x[DSTB];                 \
    _Pragma("unroll") for (int i_ = 0; i_ < (NTN); ++i_) {                      \
        int n_ = ((NT0) + i_) * 16 + l15;                                       \
        _Pragma("unroll") for (int q_ = 0; q_ < 4; ++q_) {                      \
            int m8_ = (quad * 4 + q_) & 7;                                      \
            float v_ = fmaxf(acc_[i_][q_] + biasb[(NT0) + i_], 0.f);            \
            drow_[m8_ * 64 + (((n_ >> 3) ^ m8_) << 3) + (n_ & 7)] = f2h_bits(v_); \
        }                                                                       \
    }                                                                           \
} while (0)

// ---------------- main fused kernel -----------------------------------------
// 1 block = 8 batch, 8 waves, grid 512 = 2 blocks/CU (LDS ~70 KB).
// Two nodes packed per MFMA (M 0-7 / 8-15) -> zero junk work except root.
// s_x rows [8 m][64 k]. Row map:
//   leaves 0..63 | lev0 pair t: nodes 2t,2t+1 rd 4t..4t+3 -> wr 4t,4t+2
//   (lev0 node j -> row 2j) | lev1 pair t: rd 8t,8t+2 / 8t+4,8t+6 -> 8t,8t+4
//   (lev1 node k -> row 4k) | lev2 pair t (2 waves): rd 16t,16t+4 / 16t+8,
//   16t+12 -> DEAD 16t+1,16t+2 | lev3 pair t (4 waves): rd 32t+1,32t+2 /
//   32t+17,32t+18 -> DEAD 32t+3,32t+19 (node i -> 16i+3) | lev4 (4 waves):
//   rd 3,19 / 35,51 -> DEAD 5,7 | root (4 waves, dup halves): rd 5,7 -> 1 (+9 scratch)
__global__ __launch_bounds__(NTH, 2) void formula_kernel(
    const int* __restrict__ pred_ids, const int* __restrict__ arg_ids,
    const int* __restrict__ op_ids,
    const float* __restrict__ b_pred, const float* __restrict__ b_bin,
    const float* __restrict__ b_final,
    const unsigned short* __restrict__ ws,
    float* __restrict__ out)
{
    __shared__ __align__(16) unsigned short s_x[64][512];          // 65536 B
    __shared__ __align__(8)  unsigned char  s_ids[64][8][8];       //  4096 B
    __shared__ unsigned char s_op[63 * 8 + 8];                     //   512 B

    const int tid  = threadIdx.x;
    const int b0   = blockIdx.x * NB;
    const int lane = tid & 63;
    const int w    = tid >> 6;       // wave 0..7
    const int l15  = lane & 15;
    const int quad = lane >> 4;
    const int cg   = tid & 7;        // constant col-group (leaf phase)

    // ---- stage ids: s_ids[leaf][m] = {pred, a0..a4, 0, 0} (1/thread) ----
    {
        int lf = tid >> 3, m = tid & 7;
        unsigned char* rec = &s_ids[lf][m][0];
        rec[0] = (unsigned char)pred_ids[(b0 + m) * 64 + lf];
        #pragma unroll
        for (int a = 0; a < 5; ++a)
            rec[1 + a] = (unsigned char)arg_ids[(b0 + m) * 320 + lf * 5 + a];
        rec[6] = 0; rec[7] = 0;
    }
    // ---- stage op ids [node][8 batch] ----
    if (tid < 63 * 8) {
        int r = tid >> 3, m = tid & 7;
        s_op[tid] = (unsigned char)op_ids[(b0 + m) * 63 + r];
    }

    // ---- persistent W_bin fragments: all 4 N-tiles in regs (24 VGPR) ----
    short8 wb_raw[3][2][4];
    #pragma unroll
    for (int p = 0; p < 3; ++p)
        #pragma unroll
        for (int h = 0; h < 2; ++h)
            #pragma unroll
            for (int nt = 0; nt < 4; ++nt)
                wb_raw[p][h][nt] = ld8s(ws + WBIN_OFF + (nt * 16 + l15) * 192
                                        + p * 64 + (quad + 4 * h) * 8);
    h8 (&wb)[3][2][4] = reinterpret_cast<h8(&)[3][2][4]>(wb_raw);

    float biasb[4];
    #pragma unroll
    for (int nt = 0; nt < 4; ++nt) {
        int n = nt * 16 + l15;
        biasb[nt] = (n < 50) ? b_bin[n] : 0.f;
    }
    h2 bias2[4];
    #pragma unroll
    for (int k = 0; k < 4; ++k) {
        int n0 = cg * 8 + 2 * k, n1 = n0 + 1;
        bias2[k] = (h2){(_Float16)((n0 < 50) ? b_pred[n0] : 0.f),
                        (_Float16)((n1 < 50) ? b_pred[n1] : 0.f)};
    }
    const h2 z2 = (h2){(_Float16)0.f, (_Float16)0.f};

    __syncthreads();

    // ---- leaf layer: 64 lf x 8 m x 8 cg = 4096 jobs, 8/thread,
    //      6 base-table gathers each (L1-resident 76.8 KB) ----
    #pragma unroll 4
    for (int p4 = 0; p4 < 8; ++p4) {
        int jj  = p4 * NTH + tid;          // 0..4095
        int lf  = jj >> 6;                 // 0..63
        int m   = (jj >> 3) & 7;
        const unsigned int* ivp =
            reinterpret_cast<const unsigned int*>(&s_ids[lf][m][0]);
        unsigned int ix = ivp[0], iy = ivp[1];
        int r0 = ix & 255, r1 = (ix >> 8) & 255, r2 = (ix >> 16) & 255;
        int r3 = ix >> 24, r4 = iy & 255, r5 = (iy >> 8) & 255;
        h2 a0 = bias2[0], a1 = bias2[1], a2 = bias2[2], a3 = bias2[3];
        #define ACCT(ROW, P) {                                                  \
            h8 t_ = ld8h(ws + LTAB_OFF + (P) * 6400 + (ROW) * 64 + cg * 8);     \
            const h2* tp_ = reinterpret_cast<const h2*>(&t_);                   \
            a0 += tp_[0]; a1 += tp_[1]; a2 += tp_[2]; a3 += tp_[3]; }
        ACCT(r0, 0); ACCT(r1, 1); ACCT(r2, 2);
        ACCT(r3, 3); ACCT(r4, 4); ACCT(r5, 5);
        #undef ACCT
        a0 = __builtin_elementwise_max(a0, z2);
        a1 = __builtin_elementwise_max(a1, z2);
        a2 = __builtin_elementwise_max(a2, z2);
        a3 = __builtin_elementwise_max(a3, z2);
        union { h2 h[4]; short8 s; } u;
        u.h[0] = a0; u.h[1] = a1; u.h[2] = a2; u.h[3] = a3;
        *reinterpret_cast<short8*>(
            &s_x[lf][m * 64 + ((cg ^ m) << 3)]) = u.s;
    }
    __syncthreads();

    // ---- lev0: 32 nodes = 16 pairs, 2 pair-jobs/wave ----
    #pragma unroll
    for (int i = 0; i < 2; ++i) {
        int t = w + 8 * i;
        TNODEP(0, 4, 4 * t, 4 * t + 1, 2 * t,
                     4 * t + 2, 4 * t + 3, 2 * t + 1,
                     4 * t, 4 * t + 2);
    }
    __syncthreads();
    // ---- lev1: 16 nodes = 8 pairs, 1/wave ----
    {
        int t = w;
        TNODEP(0, 4, 8 * t, 8 * t + 2, 32 + 2 * t,
                     8 * t + 4, 8 * t + 6, 32 + 2 * t + 1,
                     8 * t, 8 * t + 4);
    }
    __syncthreads();
    // ---- lev2: 8 nodes = 4 pairs, 2 waves/pair -> dead rows 16t+1,16t+2 ----
    {
        int t = w >> 1;
        if ((w & 1) == 0)
            TNODEP(0, 2, 16 * t, 16 * t + 4, 48 + 2 * t,
                         16 * t + 8, 16 * t + 12, 48 + 2 * t + 1,
                         16 * t + 1, 16 * t + 2);
        else
            TNODEP(2, 2, 16 * t, 16 * t + 4, 48 + 2 * t,
                         16 * t + 8, 16 * t + 12, 48 + 2 * t + 1,
                         16 * t + 1, 16 * t + 2);
    }
    __syncthreads();
    // ---- lev3: 4 nodes = 2 pairs, 4 waves/pair -> dead rows 32t+3,32t+19 ----
    {
        int t = w >> 2;
        switch (w & 3) {
            case 0: TNODEP(0, 1, 32*t+1, 32*t+2, 56+2*t, 32*t+17, 32*t+18, 56+2*t+1, 32*t+3, 32*t+19); break;
            case 1: TNODEP(1, 1, 32*t+1, 32*t+2, 56+2*t, 32*t+17, 32*t+18, 56+2*t+1, 32*t+3, 32*t+19); break;
            case 2: TNODEP(2, 1, 32*t+1, 32*t+2, 56+2*t, 32*t+17, 32*t+18, 56+2*t+1, 32*t+3, 32*t+19); break;
            default: TNODEP(3, 1, 32*t+1, 32*t+2, 56+2*t, 32*t+17, 32*t+18, 56+2*t+1, 32*t+3, 32*t+19); break;
        }
    }
    __syncthreads();
    // ---- lev4: 2 nodes = 1 pair, waves 0..3 -> dead rows 5,7 ----
    if (w < 4) {
        switch (w) {
            case 0: TNODEP(0, 1, 3, 19, 60, 35, 51, 61, 5, 7); break;
            case 1: TNODEP(1, 1, 3, 19, 60, 35, 51, 61, 5, 7); break;
            case 2: TNODEP(2, 1, 3, 19, 60, 35, 51, 61, 5, 7); break;
            default: TNODEP(3, 1, 3, 19, 60, 35, 51, 61, 5, 7); break;
        }
    }
    __syncthreads();
    // ---- root: single node duplicated in both halves -> row 1 (+9 scratch) ----
    if (w < 4) {
        switch (w) {
            case 0: TNODEP(0, 1, 5, 7, 62, 5, 7, 62, 1, 9); break;
            case 1: TNODEP(1, 1, 5, 7, 62, 5, 7, 62, 1, 9); break;
            case 2: TNODEP(2, 1, 5, 7, 62, 5, 7, 62, 1, 9); break;
            default: TNODEP(3, 1, 5, 7, 62, 5, 7, 62, 1, 9); break;
        }
    }
    __syncthreads();

    // ---- final head via MFMA: 10 N-tiles over 8 waves (root = row 1) ----
    auto headtile = [&](int t) {
        f32x4 acc = {0.f, 0.f, 0.f, 0.f};
        int n2 = t * 16 + l15;
        const unsigned short* rroot = s_x[1];
        int mr = l15 & 7;
        h8 x0 = ld8h(rroot + mr * 64 + ((quad ^ mr) << 3));
        h8 x1 = ld8h(rroot + mr * 64 + (((quad + 4) ^ mr) << 3));
        acc = mf(x0, ld8h(ws + WFIN_OFF + n2 * 64 + quad * 8), acc);
        acc = mf(x1, ld8h(ws + WFIN_OFF + n2 * 64 + (quad + 4) * 8), acc);
        if (n2 < 155) {
            float bias = b_final[n2];
            #pragma unroll
            for (int q = 0; q < 4; ++q) {
                int m = quad * 4 + q;
                if (m < NB) out[(b0 + m) * 155 + n2] = acc[q] + bias;
            }
        }
    };
    headtile(w);
    if (w < 2) headtile(8 + w);
}

extern "C" void kernel_launch(void* const* d_in, const int* in_sizes, int n_in,
                              void* d_out, int out_size, void* d_ws, size_t ws_size,
                              hipStream_t stream) {
    const int*   pred_ids = (const int*)  d_in[0];
    const int*   arg_ids  = (const int*)  d_in[1];
    const int*   op_ids   = (const int*)  d_in[2];
    const float* emb_pred = (const float*)d_in[3];
    const float* emb_var  = (const float*)d_in[4];
    const float* emb_op   = (const float*)d_in[5];
    const float* W_pred   = (const float*)d_in[6];
    const float* b_pred   = (const float*)d_in[7];
    const float* W_bin    = (const float*)d_in[8];
    const float* b_bin    = (const float*)d_in[9];
    const float* W_final  = (const float*)d_in[10];
    const float* b_final  = (const float*)d_in[11];
    unsigned short* ws = (unsigned short*)d_ws;
    float* out = (float*)d_out;

    hipLaunchKernelGGL(prep_kernel, dim3(256), dim3(256), 0, stream,
                       emb_pred, emb_var, emb_op, W_pred, W_bin, W_final, ws);
    hipLaunchKernelGGL(formula_kernel, dim3(4096 / NB), dim3(NTH), 0, stream,
                       pred_ids, arg_ids, op_ids, b_pred, b_bin, b_final,
                       (const unsigned short*)ws, out);
}